// Round 2
// baseline (853.683 us; speedup 1.0000x reference)
//
#include <hip/hip_runtime.h>
#include <math.h>

#define NFEAT 256
#define NHID 128
#define NCLASS 40

typedef unsigned short ushort_t;
typedef unsigned int uint_t;

static __device__ inline float bf2f(ushort_t u) {
    union { uint_t u; float f; } v; v.u = (uint_t)u << 16; return v.f;
}
static __device__ inline ushort_t f2bf(float f) {
    uint_t u = __float_as_uint(f);
    u += 0x7FFF + ((u >> 16) & 1);           // round-to-nearest-even
    return (ushort_t)(u >> 16);
}

// ---------------- degree / CSR build ----------------

__global__ void k_init(int* cnt, int* cursor, int n) {
    int i = blockIdx.x * blockDim.x + threadIdx.x;
    if (i < n) { cnt[i] = 0; cursor[i] = 0; }
}

__global__ void k_count(const int* __restrict__ dst, int* __restrict__ cnt, int E) {
    int e = blockIdx.x * blockDim.x + threadIdx.x;
    if (e < E) atomicAdd(&cnt[dst[e]], 1);
}

__global__ void k_dinv(const int* __restrict__ cnt, float* __restrict__ dinv, int n) {
    int i = blockIdx.x * blockDim.x + threadIdx.x;
    if (i < n) dinv[i] = rsqrtf((float)cnt[i] + 1.0f);
}

// exclusive scan, 2048 elements/block (256 thr x 8)
__global__ void k_scan_local(const int* __restrict__ in, int* __restrict__ out,
                             int* __restrict__ bsum, int n) {
    __shared__ int ts[256];
    int tid = threadIdx.x;
    int base = blockIdx.x * 2048 + tid * 8;
    int v[8]; int s = 0;
#pragma unroll
    for (int i = 0; i < 8; i++) { int idx = base + i; v[i] = (idx < n) ? in[idx] : 0; s += v[i]; }
    ts[tid] = s;
    __syncthreads();
    for (int off = 1; off < 256; off <<= 1) {
        int t = (tid >= off) ? ts[tid - off] : 0;
        __syncthreads();
        ts[tid] += t;
        __syncthreads();
    }
    int run = ts[tid] - s;
#pragma unroll
    for (int i = 0; i < 8; i++) { int idx = base + i; if (idx < n) out[idx] = run; run += v[i]; }
    if (tid == 255) bsum[blockIdx.x] = ts[255];
}

__global__ void k_scan_bsum(int* bsum, int nb) {
    int tid = threadIdx.x;           // single wave of 64, nb <= 64
    int v = (tid < nb) ? bsum[tid] : 0;
    int orig = v;
    for (int off = 1; off < 64; off <<= 1) {
        int t = __shfl_up(v, off, 64);
        if (tid >= off) v += t;
    }
    if (tid < nb) bsum[tid] = v - orig;   // exclusive block offsets
}

__global__ void k_scan_add(int* __restrict__ out, const int* __restrict__ bsum, int n, int E) {
    int b = blockIdx.x;
    int base = b * 2048 + threadIdx.x * 8;
    int add = bsum[b];
#pragma unroll
    for (int i = 0; i < 8; i++) { int idx = base + i; if (idx < n) out[idx] += add; }
    if (b == 0 && threadIdx.x == 0) out[n] = E;
}

__global__ void k_fill(const int* __restrict__ src, const int* __restrict__ dst,
                       const int* __restrict__ row_ptr, int* __restrict__ cursor,
                       int* __restrict__ col, int E) {
    int e = blockIdx.x * blockDim.x + threadIdx.x;
    if (e < E) {
        int d = dst[e];
        int p = row_ptr[d] + atomicAdd(&cursor[d], 1);
        col[p] = src[e];
    }
}

// ---------------- GEMM: C[n,128] = A[n,K] @ W[K,128], bf16 out ----------------
// block tile 64x128, 256 threads, micro-tile 4x8

template<int K>
__global__ __launch_bounds__(256) void k_gemm_bn128(const float* __restrict__ A,
                                                    const float* __restrict__ W,
                                                    ushort_t* __restrict__ C, int n) {
    const int BM = 64, BN = 128, BK = 64;
    __shared__ float As[BK][BM + 4];   // transposed A tile
    __shared__ float Ws[BK][BN + 4];
    const int tid = threadIdx.x;
    const int tx = tid & 15, ty = tid >> 4;
    const int row0 = blockIdx.x * BM;
    float acc[4][8];
#pragma unroll
    for (int i = 0; i < 4; i++)
#pragma unroll
        for (int j = 0; j < 8; j++) acc[i][j] = 0.f;

    for (int k0 = 0; k0 < K; k0 += BK) {
#pragma unroll
        for (int p = 0; p < 4; p++) {
            int r = p * 16 + ty;        // 0..63 tile row
            int c = tx * 4;             // 0..60 tile col (k)
            float4 v = make_float4(0.f, 0.f, 0.f, 0.f);
            if (row0 + r < n) v = *(const float4*)&A[(size_t)(row0 + r) * K + k0 + c];
            As[c + 0][r] = v.x; As[c + 1][r] = v.y; As[c + 2][r] = v.z; As[c + 3][r] = v.w;
        }
#pragma unroll
        for (int p = 0; p < 8; p++) {
            int r = p * 8 + (tid >> 5);
            int c = (tid & 31) * 4;
            *(float4*)&Ws[r][c] = *(const float4*)&W[(size_t)(k0 + r) * BN + c];
        }
        __syncthreads();
#pragma unroll
        for (int kk = 0; kk < BK; kk++) {
            float4 a  = *(const float4*)&As[kk][ty * 4];
            float4 bq0 = *(const float4*)&Ws[kk][tx * 4];
            float4 bq1 = *(const float4*)&Ws[kk][tx * 4 + 64];
            float av[4] = {a.x, a.y, a.z, a.w};
            float bv[8] = {bq0.x, bq0.y, bq0.z, bq0.w, bq1.x, bq1.y, bq1.z, bq1.w};
#pragma unroll
            for (int i = 0; i < 4; i++)
#pragma unroll
                for (int j = 0; j < 8; j++) acc[i][j] = fmaf(av[i], bv[j], acc[i][j]);
        }
        __syncthreads();
    }
#pragma unroll
    for (int i = 0; i < 4; i++) {
        int row = row0 + ty * 4 + i;
        if (row < n) {
            ushort4 v0, v1;
            v0.x = f2bf(acc[i][0]); v0.y = f2bf(acc[i][1]); v0.z = f2bf(acc[i][2]); v0.w = f2bf(acc[i][3]);
            v1.x = f2bf(acc[i][4]); v1.y = f2bf(acc[i][5]); v1.z = f2bf(acc[i][6]); v1.w = f2bf(acc[i][7]);
            *(ushort4*)&C[(size_t)row * BN + tx * 4]      = v0;
            *(ushort4*)&C[(size_t)row * BN + 64 + tx * 4] = v1;
        }
    }
}

// ---------------- GEMM: C[n,40] = A[n,128] @ W[128,40], bf16 out ----------------

__global__ __launch_bounds__(256) void k_gemm40(const float* __restrict__ A,
                                                const float* __restrict__ W,
                                                ushort_t* __restrict__ C, int n) {
    const int BM = 64, K = 128, BN = 40;
    __shared__ float As[BM][K + 4];
    __shared__ float Ws[K * BN];
    int tid = threadIdx.x;
    int row0 = blockIdx.x * BM;
#pragma unroll
    for (int p = 0; p < 5; p++) {                  // 1280 float4 of W
        int i = p * 256 + tid;
        *(float4*)&Ws[i * 4] = *(const float4*)&W[i * 4];
    }
#pragma unroll
    for (int p = 0; p < 8; p++) {
        int r = p * 8 + (tid >> 5);
        int c = (tid & 31) * 4;
        float4 v = make_float4(0.f, 0.f, 0.f, 0.f);
        if (row0 + r < n) v = *(const float4*)&A[(size_t)(row0 + r) * K + c];
        *(float4*)&As[r][c] = v;
    }
    __syncthreads();
    int tx = tid & 7, ty = tid >> 3;
    int r0 = ty * 2, c0 = tx * 5;
    float acc[2][5];
#pragma unroll
    for (int i = 0; i < 2; i++)
#pragma unroll
        for (int j = 0; j < 5; j++) acc[i][j] = 0.f;
#pragma unroll 8
    for (int k = 0; k < K; k++) {
        float a0 = As[r0][k], a1 = As[r0 + 1][k];
#pragma unroll
        for (int j = 0; j < 5; j++) {
            float w = Ws[k * BN + c0 + j];
            acc[0][j] = fmaf(a0, w, acc[0][j]);
            acc[1][j] = fmaf(a1, w, acc[1][j]);
        }
    }
#pragma unroll
    for (int i = 0; i < 2; i++) {
        int row = row0 + r0 + i;
        if (row < n) {
#pragma unroll
            for (int j = 0; j < 5; j++) C[(size_t)row * BN + c0 + j] = f2bf(acc[i][j]);
        }
    }
}

// ---------------- aggregation (gather over CSR-by-dst, bf16 h) ----------------
// one wave per node, 2 features per lane (ushort2 = 4B loads)

template<bool RELU>
__global__ __launch_bounds__(256) void k_agg128(const ushort_t* __restrict__ h,
                                                const float* __restrict__ dinv,
                                                const int* __restrict__ row_ptr,
                                                const int* __restrict__ col,
                                                const float* __restrict__ bias,
                                                float* __restrict__ out, int N) {
    int n = blockIdx.x * 4 + (threadIdx.x >> 6);
    if (n >= N) return;
    int lane = threadIdx.x & 63;
    float dn = dinv[n];
    ushort2 hv = *(const ushort2*)&h[(size_t)n * NHID + lane * 2];
    float acc0 = dn * bf2f(hv.x);
    float acc1 = dn * bf2f(hv.y);
    int e1 = row_ptr[n + 1];
    for (int e = row_ptr[n]; e < e1; ++e) {
        int s = col[e];
        float ds = dinv[s];
        ushort2 v = *(const ushort2*)&h[(size_t)s * NHID + lane * 2];
        acc0 = fmaf(ds, bf2f(v.x), acc0);
        acc1 = fmaf(ds, bf2f(v.y), acc1);
    }
    float r0 = fmaf(dn, acc0, bias[lane * 2]);
    float r1 = fmaf(dn, acc1, bias[lane * 2 + 1]);
    if (RELU) { r0 = fmaxf(r0, 0.f); r1 = fmaxf(r1, 0.f); }
    *(float2*)&out[(size_t)n * NHID + lane * 2] = make_float2(r0, r1);
}

__global__ __launch_bounds__(256) void k_agg40_lsm(const ushort_t* __restrict__ h,
                                                   const float* __restrict__ dinv,
                                                   const int* __restrict__ row_ptr,
                                                   const int* __restrict__ col,
                                                   const float* __restrict__ bias,
                                                   float* __restrict__ out, int N) {
    int n = blockIdx.x * 4 + (threadIdx.x >> 6);
    if (n >= N) return;
    int lane = threadIdx.x & 63;
    bool act = lane < (NCLASS / 2);
    float dn = dinv[n];
    float acc0 = 0.f, acc1 = 0.f;
    if (act) {
        ushort2 hv = *(const ushort2*)&h[(size_t)n * NCLASS + lane * 2];
        acc0 = dn * bf2f(hv.x);
        acc1 = dn * bf2f(hv.y);
    }
    int e1 = row_ptr[n + 1];
    for (int e = row_ptr[n]; e < e1; ++e) {
        int s = col[e];
        float ds = dinv[s];
        if (act) {
            ushort2 v = *(const ushort2*)&h[(size_t)s * NCLASS + lane * 2];
            acc0 = fmaf(ds, bf2f(v.x), acc0);
            acc1 = fmaf(ds, bf2f(v.y), acc1);
        }
    }
    float z0 = act ? fmaf(dn, acc0, bias[lane * 2])     : -INFINITY;
    float z1 = act ? fmaf(dn, acc1, bias[lane * 2 + 1]) : -INFINITY;
    float m = fmaxf(z0, z1);
#pragma unroll
    for (int off = 32; off; off >>= 1) m = fmaxf(m, __shfl_xor(m, off, 64));
    float p = act ? (expf(z0 - m) + expf(z1 - m)) : 0.f;
#pragma unroll
    for (int off = 32; off; off >>= 1) p += __shfl_xor(p, off, 64);
    float lse = logf(p);
    if (act)
        *(float2*)&out[(size_t)n * NCLASS + lane * 2] =
            make_float2(z0 - m - lse, z1 - m - lse);
}

// ---------------- launch ----------------

extern "C" void kernel_launch(void* const* d_in, const int* in_sizes, int n_in,
                              void* d_out, int out_size, void* d_ws, size_t ws_size,
                              hipStream_t stream) {
    const float* x  = (const float*)d_in[0];
    const int*   ei = (const int*)d_in[1];
    const float* W1 = (const float*)d_in[2];
    const float* b1 = (const float*)d_in[3];
    const float* W2 = (const float*)d_in[4];
    const float* b2 = (const float*)d_in[5];
    const float* W3 = (const float*)d_in[6];
    const float* b3 = (const float*)d_in[7];
    float* out = (float*)d_out;
    const int N = in_sizes[0] / NFEAT;
    const int E = in_sizes[1] / 2;
    const int* src = ei;
    const int* dst = ei + E;

    char* ws = (char*)d_ws;
    size_t off = 0;
    auto alloc = [&](size_t bytes) -> void* {
        void* p = ws + off;
        off += (bytes + 255) & ~(size_t)255;
        return p;
    };
    int*      cnt     = (int*)alloc((size_t)N * 4);
    float*    dinv    = (float*)alloc((size_t)N * 4);
    int*      cursor  = (int*)alloc((size_t)N * 4);
    int*      row_ptr = (int*)alloc((size_t)(N + 1) * 4);
    int*      bsum    = (int*)alloc(64 * 4);
    int*      col     = (int*)alloc((size_t)E * 4);
    ushort_t* hbuf    = (ushort_t*)alloc((size_t)N * NHID * 2);  // bf16 GEMM out
    float*    abuf    = (float*)alloc((size_t)N * NHID * 4);     // fp32 activations
    (void)ws_size; (void)n_in; (void)out_size;

    int NB = (N + 2047) / 2048;

    k_init<<<(N + 255) / 256, 256, 0, stream>>>(cnt, cursor, N);
    k_count<<<(E + 255) / 256, 256, 0, stream>>>(dst, cnt, E);
    k_dinv<<<(N + 255) / 256, 256, 0, stream>>>(cnt, dinv, N);
    k_scan_local<<<NB, 256, 0, stream>>>(cnt, row_ptr, bsum, N);
    k_scan_bsum<<<1, 64, 0, stream>>>(bsum, NB);
    k_scan_add<<<NB, 256, 0, stream>>>(row_ptr, bsum, N, E);
    k_fill<<<(E + 255) / 256, 256, 0, stream>>>(src, dst, row_ptr, cursor, col, E);

    int nagg = (N + 3) / 4;
    // layer 1: h1 = x @ W1 (bf16) ; a1 = relu(agg(h1)+b1) (fp32)
    k_gemm_bn128<NFEAT><<<(N + 63) / 64, 256, 0, stream>>>(x, W1, hbuf, N);
    k_agg128<true><<<nagg, 256, 0, stream>>>(hbuf, dinv, row_ptr, col, b1, abuf, N);
    // layer 2
    k_gemm_bn128<NHID><<<(N + 63) / 64, 256, 0, stream>>>(abuf, W2, hbuf, N);
    k_agg128<true><<<nagg, 256, 0, stream>>>(hbuf, dinv, row_ptr, col, b2, abuf, N);
    // layer 3 + log_softmax
    k_gemm40<<<(N + 63) / 64, 256, 0, stream>>>(abuf, W3, hbuf, N);
    k_agg40_lsm<<<nagg, 256, 0, stream>>>(hbuf, dinv, row_ptr, col, b3, out, N);
}

// Round 3
// 500.414 us; speedup vs baseline: 1.7060x; 1.7060x over previous
//
#include <hip/hip_runtime.h>
#include <math.h>

#define NFEAT 256
#define NHID 128
#define NCLASS 40

typedef unsigned short ushort_t;
typedef unsigned int uint_t;
typedef __attribute__((ext_vector_type(8))) short bf16x8;
typedef __attribute__((ext_vector_type(4))) float f32x4;

static __device__ inline float bf2f(ushort_t u) {
    union { uint_t u; float f; } v; v.u = (uint_t)u << 16; return v.f;
}
static __device__ inline ushort_t f2bf(float f) {
    uint_t u = __float_as_uint(f);
    u += 0x7FFF + ((u >> 16) & 1);           // round-to-nearest-even
    return (ushort_t)(u >> 16);
}

// ---------------- degree / CSR build ----------------

__global__ void k_init(int* cnt, int* cursor, int n) {
    int i = blockIdx.x * blockDim.x + threadIdx.x;
    if (i < n) { cnt[i] = 0; cursor[i] = 0; }
}

__global__ void k_count(const int* __restrict__ dst, int* __restrict__ cnt, int E) {
    int e = blockIdx.x * blockDim.x + threadIdx.x;
    if (e < E) atomicAdd(&cnt[dst[e]], 1);
}

__global__ void k_dinv(const int* __restrict__ cnt, float* __restrict__ dinv, int n) {
    int i = blockIdx.x * blockDim.x + threadIdx.x;
    if (i < n) dinv[i] = rsqrtf((float)cnt[i] + 1.0f);
}

// exclusive scan, 2048 elements/block (256 thr x 8)
__global__ void k_scan_local(const int* __restrict__ in, int* __restrict__ out,
                             int* __restrict__ bsum, int n) {
    __shared__ int ts[256];
    int tid = threadIdx.x;
    int base = blockIdx.x * 2048 + tid * 8;
    int v[8]; int s = 0;
#pragma unroll
    for (int i = 0; i < 8; i++) { int idx = base + i; v[i] = (idx < n) ? in[idx] : 0; s += v[i]; }
    ts[tid] = s;
    __syncthreads();
    for (int off = 1; off < 256; off <<= 1) {
        int t = (tid >= off) ? ts[tid - off] : 0;
        __syncthreads();
        ts[tid] += t;
        __syncthreads();
    }
    int run = ts[tid] - s;
#pragma unroll
    for (int i = 0; i < 8; i++) { int idx = base + i; if (idx < n) out[idx] = run; run += v[i]; }
    if (tid == 255) bsum[blockIdx.x] = ts[255];
}

__global__ void k_scan_bsum(int* bsum, int nb) {
    int tid = threadIdx.x;           // single wave of 64, nb <= 64
    int v = (tid < nb) ? bsum[tid] : 0;
    int orig = v;
    for (int off = 1; off < 64; off <<= 1) {
        int t = __shfl_up(v, off, 64);
        if (tid >= off) v += t;
    }
    if (tid < nb) bsum[tid] = v - orig;   // exclusive block offsets
}

__global__ void k_scan_add(int* __restrict__ out, const int* __restrict__ bsum, int n, int E) {
    int b = blockIdx.x;
    int base = b * 2048 + threadIdx.x * 8;
    int add = bsum[b];
#pragma unroll
    for (int i = 0; i < 8; i++) { int idx = base + i; if (idx < n) out[idx] += add; }
    if (b == 0 && threadIdx.x == 0) out[n] = E;
}

__global__ void k_fill(const int* __restrict__ src, const int* __restrict__ dst,
                       const int* __restrict__ row_ptr, int* __restrict__ cursor,
                       int* __restrict__ col, int E) {
    int e = blockIdx.x * blockDim.x + threadIdx.x;
    if (e < E) {
        int d = dst[e];
        int p = row_ptr[d] + atomicAdd(&cursor[d], 1);
        col[p] = src[e];
    }
}

// ---------------- weight transpose + hi/lo bf16 split ----------------
// W[K][Nw] fp32 -> Whi/Wlo[Npad][K] bf16 (rows >= Nw zero)

__global__ void k_wt(const float* __restrict__ W, ushort_t* __restrict__ Whi,
                     ushort_t* __restrict__ Wlo, int K, int Nw, int Npad) {
    int idx = blockIdx.x * blockDim.x + threadIdx.x;
    if (idx >= Npad * K) return;
    int nrow = idx / K, k = idx - nrow * K;
    float w = (nrow < Nw) ? W[(size_t)k * Nw + nrow] : 0.f;
    ushort_t hi = f2bf(w);
    Whi[idx] = hi;
    Wlo[idx] = f2bf(w - bf2f(hi));
}

// ---------------- MFMA GEMM: C[n, NOUT] = A[n, K] @ W[K, NOUT], bf16 out ----
// block = 256 thr (4 waves), tile 64 x BN, K-step 32
// W passed pre-transposed/split: Whi/Wlo[BN][K] bf16
// mfma_f32_16x16x32_bf16 layouts: A: m=l%16, k=(l>>4)*8+i ; B: n=l%16, k=(l>>4)*8+i
// D: n=l&15, m=(l>>4)*4+reg   [measured: learn_hip m89]

template<int K, bool A_FP32, int BN, int NOUT>
__global__ __launch_bounds__(256) void k_gemm_mfma(const void* __restrict__ Ap,
                                                   const ushort_t* __restrict__ Whi,
                                                   const ushort_t* __restrict__ Wlo,
                                                   ushort_t* __restrict__ C, int n) {
    const int BM = 64, BK = 32;
    const int LDA = BK + 8;                    // 40 ushorts -> 80 B row stride (2-way LDS conflict = free)
    __shared__ ushort_t As[BM][LDA];
    __shared__ ushort_t Bh[BN][LDA];
    __shared__ ushort_t Bl[BN][LDA];
    const int tid = threadIdx.x;
    const int w = tid >> 6, l = tid & 63;
    const int row0 = blockIdx.x * BM;
    const int NJ = BN / 16;
    f32x4 acc[NJ] = {};

    for (int k0 = 0; k0 < K; k0 += BK) {
        // stage A tile (64 x 32), convert to bf16 if fp32
        {
            int r = tid >> 2, c = (tid & 3) * 8;
            if (A_FP32) {
                const float* A = (const float*)Ap;
                float4 v0 = make_float4(0.f, 0.f, 0.f, 0.f);
                float4 v1 = make_float4(0.f, 0.f, 0.f, 0.f);
                if (row0 + r < n) {
                    v0 = *(const float4*)&A[(size_t)(row0 + r) * K + k0 + c];
                    v1 = *(const float4*)&A[(size_t)(row0 + r) * K + k0 + c + 4];
                }
                ushort_t* p = &As[r][c];
                p[0] = f2bf(v0.x); p[1] = f2bf(v0.y); p[2] = f2bf(v0.z); p[3] = f2bf(v0.w);
                p[4] = f2bf(v1.x); p[5] = f2bf(v1.y); p[6] = f2bf(v1.z); p[7] = f2bf(v1.w);
            } else {
                const ushort_t* A = (const ushort_t*)Ap;
                ushort4 v0 = {0, 0, 0, 0}, v1 = {0, 0, 0, 0};
                if (row0 + r < n) {
                    v0 = *(const ushort4*)&A[(size_t)(row0 + r) * K + k0 + c];
                    v1 = *(const ushort4*)&A[(size_t)(row0 + r) * K + k0 + c + 4];
                }
                *(ushort4*)&As[r][c] = v0;
                *(ushort4*)&As[r][c + 4] = v1;
            }
        }
        // stage B tiles (BN x 32, hi + lo)
        for (int idx = tid; idx < BN * 4; idx += 256) {
            int r = idx >> 2, c = (idx & 3) * 8;
            *(ushort4*)&Bh[r][c]     = *(const ushort4*)&Whi[(size_t)r * K + k0 + c];
            *(ushort4*)&Bh[r][c + 4] = *(const ushort4*)&Whi[(size_t)r * K + k0 + c + 4];
            *(ushort4*)&Bl[r][c]     = *(const ushort4*)&Wlo[(size_t)r * K + k0 + c];
            *(ushort4*)&Bl[r][c + 4] = *(const ushort4*)&Wlo[(size_t)r * K + k0 + c + 4];
        }
        __syncthreads();

        const int ko = (l >> 4) * 8;
        bf16x8 a = *(const bf16x8*)&As[w * 16 + (l & 15)][ko];
#pragma unroll
        for (int j = 0; j < NJ; j++) {
            bf16x8 bh = *(const bf16x8*)&Bh[j * 16 + (l & 15)][ko];
            bf16x8 bl = *(const bf16x8*)&Bl[j * 16 + (l & 15)][ko];
            acc[j] = __builtin_amdgcn_mfma_f32_16x16x32_bf16(a, bh, acc[j], 0, 0, 0);
            acc[j] = __builtin_amdgcn_mfma_f32_16x16x32_bf16(a, bl, acc[j], 0, 0, 0);
        }
        __syncthreads();
    }

#pragma unroll
    for (int j = 0; j < NJ; j++) {
        int colb = j * 16 + (l & 15);
#pragma unroll
        for (int r = 0; r < 4; r++) {
            int row = row0 + w * 16 + (l >> 4) * 4 + r;
            if (row < n && colb < NOUT)
                C[(size_t)row * NOUT + colb] = f2bf(acc[j][r]);
        }
    }
}

// ---------------- aggregation (gather over CSR-by-dst, bf16 h) ----------------
// one wave per node, 2 features per lane, edge loop unrolled x8 for MLP

template<bool RELU>
__global__ __launch_bounds__(256) void k_agg128(const ushort_t* __restrict__ h,
                                                const float* __restrict__ dinv,
                                                const int* __restrict__ rp,
                                                const int* __restrict__ col,
                                                const float* __restrict__ bias,
                                                ushort_t* __restrict__ out, int N) {
    int n = blockIdx.x * 4 + (threadIdx.x >> 6);
    if (n >= N) return;
    int lane = threadIdx.x & 63;
    float dn = dinv[n];
    ushort2 hv = *(const ushort2*)&h[(size_t)n * NHID + lane * 2];
    float acc0 = dn * bf2f(hv.x), acc1 = dn * bf2f(hv.y);
    int e = rp[n], e1 = rp[n + 1];
    for (; e + 8 <= e1; e += 8) {
        int s[8]; float d[8]; ushort2 v[8];
#pragma unroll
        for (int i = 0; i < 8; i++) s[i] = col[e + i];
#pragma unroll
        for (int i = 0; i < 8; i++) d[i] = dinv[s[i]];
#pragma unroll
        for (int i = 0; i < 8; i++) v[i] = *(const ushort2*)&h[(size_t)s[i] * NHID + lane * 2];
#pragma unroll
        for (int i = 0; i < 8; i++) {
            acc0 = fmaf(d[i], bf2f(v[i].x), acc0);
            acc1 = fmaf(d[i], bf2f(v[i].y), acc1);
        }
    }
    for (; e < e1; ++e) {
        int s = col[e];
        float d = dinv[s];
        ushort2 v = *(const ushort2*)&h[(size_t)s * NHID + lane * 2];
        acc0 = fmaf(d, bf2f(v.x), acc0);
        acc1 = fmaf(d, bf2f(v.y), acc1);
    }
    float r0 = fmaf(dn, acc0, bias[lane * 2]);
    float r1 = fmaf(dn, acc1, bias[lane * 2 + 1]);
    if (RELU) { r0 = fmaxf(r0, 0.f); r1 = fmaxf(r1, 0.f); }
    ushort2 o; o.x = f2bf(r0); o.y = f2bf(r1);
    *(ushort2*)&out[(size_t)n * NHID + lane * 2] = o;
}

__global__ __launch_bounds__(256) void k_agg40_lsm(const ushort_t* __restrict__ h,
                                                   const float* __restrict__ dinv,
                                                   const int* __restrict__ rp,
                                                   const int* __restrict__ col,
                                                   const float* __restrict__ bias,
                                                   float* __restrict__ out, int N) {
    int n = blockIdx.x * 4 + (threadIdx.x >> 6);
    if (n >= N) return;
    int lane = threadIdx.x & 63;
    bool act = lane < (NCLASS / 2);
    float dn = dinv[n];
    float acc0 = 0.f, acc1 = 0.f;
    if (act) {
        ushort2 hv = *(const ushort2*)&h[(size_t)n * NCLASS + lane * 2];
        acc0 = dn * bf2f(hv.x);
        acc1 = dn * bf2f(hv.y);
    }
    int e = rp[n], e1 = rp[n + 1];
    for (; e + 8 <= e1; e += 8) {
        int s[8]; float d[8]; ushort2 v[8];
#pragma unroll
        for (int i = 0; i < 8; i++) s[i] = col[e + i];
#pragma unroll
        for (int i = 0; i < 8; i++) d[i] = dinv[s[i]];
#pragma unroll
        for (int i = 0; i < 8; i++)
            v[i] = act ? *(const ushort2*)&h[(size_t)s[i] * NCLASS + lane * 2]
                       : make_ushort2(0, 0);
#pragma unroll
        for (int i = 0; i < 8; i++) {
            acc0 = fmaf(d[i], bf2f(v[i].x), acc0);
            acc1 = fmaf(d[i], bf2f(v[i].y), acc1);
        }
    }
    for (; e < e1; ++e) {
        int s = col[e];
        float d = dinv[s];
        if (act) {
            ushort2 v = *(const ushort2*)&h[(size_t)s * NCLASS + lane * 2];
            acc0 = fmaf(d, bf2f(v.x), acc0);
            acc1 = fmaf(d, bf2f(v.y), acc1);
        }
    }
    float z0 = act ? fmaf(dn, acc0, bias[lane * 2])     : -INFINITY;
    float z1 = act ? fmaf(dn, acc1, bias[lane * 2 + 1]) : -INFINITY;
    float m = fmaxf(z0, z1);
#pragma unroll
    for (int off = 32; off; off >>= 1) m = fmaxf(m, __shfl_xor(m, off, 64));
    float p = act ? (expf(z0 - m) + expf(z1 - m)) : 0.f;
#pragma unroll
    for (int off = 32; off; off >>= 1) p += __shfl_xor(p, off, 64);
    float lse = logf(p);
    if (act)
        *(float2*)&out[(size_t)n * NCLASS + lane * 2] =
            make_float2(z0 - m - lse, z1 - m - lse);
}

// ---------------- launch ----------------

extern "C" void kernel_launch(void* const* d_in, const int* in_sizes, int n_in,
                              void* d_out, int out_size, void* d_ws, size_t ws_size,
                              hipStream_t stream) {
    const float* x  = (const float*)d_in[0];
    const int*   ei = (const int*)d_in[1];
    const float* W1 = (const float*)d_in[2];
    const float* b1 = (const float*)d_in[3];
    const float* W2 = (const float*)d_in[4];
    const float* b2 = (const float*)d_in[5];
    const float* W3 = (const float*)d_in[6];
    const float* b3 = (const float*)d_in[7];
    float* out = (float*)d_out;
    const int N = in_sizes[0] / NFEAT;
    const int E = in_sizes[1] / 2;
    const int* src = ei;
    const int* dst = ei + E;

    char* ws = (char*)d_ws;
    size_t off = 0;
    auto alloc = [&](size_t bytes) -> void* {
        void* p = ws + off;
        off += (bytes + 255) & ~(size_t)255;
        return p;
    };
    int*      cnt     = (int*)alloc((size_t)N * 4);
    float*    dinv    = (float*)alloc((size_t)N * 4);
    int*      cursor  = (int*)alloc((size_t)N * 4);
    int*      row_ptr = (int*)alloc((size_t)(N + 1) * 4);
    int*      bsum    = (int*)alloc(64 * 4);
    int*      col     = (int*)alloc((size_t)E * 4);
    ushort_t* hbuf    = (ushort_t*)alloc((size_t)N * NHID * 2);  // GEMM out (bf16)
    ushort_t* abuf    = (ushort_t*)alloc((size_t)N * NHID * 2);  // activations (bf16)
    ushort_t* Whi1    = (ushort_t*)alloc((size_t)NHID * NFEAT * 2);
    ushort_t* Wlo1    = (ushort_t*)alloc((size_t)NHID * NFEAT * 2);
    ushort_t* Whi2    = (ushort_t*)alloc((size_t)NHID * NHID * 2);
    ushort_t* Wlo2    = (ushort_t*)alloc((size_t)NHID * NHID * 2);
    ushort_t* Whi3    = (ushort_t*)alloc((size_t)48 * NHID * 2);
    ushort_t* Wlo3    = (ushort_t*)alloc((size_t)48 * NHID * 2);
    (void)ws_size; (void)n_in; (void)out_size;

    int NB = (N + 2047) / 2048;

    // weight prep
    k_wt<<<(NHID * NFEAT + 255) / 256, 256, 0, stream>>>(W1, Whi1, Wlo1, NFEAT, NHID, NHID);
    k_wt<<<(NHID * NHID + 255) / 256, 256, 0, stream>>>(W2, Whi2, Wlo2, NHID, NHID, NHID);
    k_wt<<<(48 * NHID + 255) / 256, 256, 0, stream>>>(W3, Whi3, Wlo3, NHID, NCLASS, 48);

    // CSR build
    k_init<<<(N + 255) / 256, 256, 0, stream>>>(cnt, cursor, N);
    k_count<<<(E + 255) / 256, 256, 0, stream>>>(dst, cnt, E);
    k_dinv<<<(N + 255) / 256, 256, 0, stream>>>(cnt, dinv, N);
    k_scan_local<<<NB, 256, 0, stream>>>(cnt, row_ptr, bsum, N);
    k_scan_bsum<<<1, 64, 0, stream>>>(bsum, NB);
    k_scan_add<<<NB, 256, 0, stream>>>(row_ptr, bsum, N, E);
    k_fill<<<(E + 255) / 256, 256, 0, stream>>>(src, dst, row_ptr, cursor, col, E);

    int ngemm = (N + 63) / 64;
    int nagg = (N + 3) / 4;
    // layer 1
    k_gemm_mfma<NFEAT, true, 128, 128><<<ngemm, 256, 0, stream>>>(x, Whi1, Wlo1, hbuf, N);
    k_agg128<true><<<nagg, 256, 0, stream>>>(hbuf, dinv, row_ptr, col, b1, abuf, N);
    // layer 2
    k_gemm_mfma<NHID, false, 128, 128><<<ngemm, 256, 0, stream>>>(abuf, Whi2, Wlo2, hbuf, N);
    k_agg128<true><<<nagg, 256, 0, stream>>>(hbuf, dinv, row_ptr, col, b2, abuf, N);
    // layer 3 + log_softmax
    k_gemm_mfma<NHID, false, 48, NCLASS><<<ngemm, 256, 0, stream>>>(abuf, Whi3, Wlo3, hbuf, N);
    k_agg40_lsm<<<nagg, 256, 0, stream>>>(hbuf, dinv, row_ptr, col, b3, out, N);
}